// Round 7
// baseline (134.802 us; speedup 1.0000x reference)
//
#include <hip/hip_runtime.h>

#define G_TOT 2016
#define NGB32 63
#define HSTR 40   // hbuf row stride in f16 (80B): fragment-contiguous, 2-way banks
#define CSTR 33   // cob row stride (f32)

typedef _Float16 f16;
typedef __attribute__((ext_vector_type(2))) _Float16 v2h;
typedef __attribute__((ext_vector_type(4))) _Float16 v4h;
typedef __attribute__((ext_vector_type(8))) _Float16 v8h;
typedef __attribute__((ext_vector_type(4))) float v4f;

__device__ __forceinline__ v2h pkrtz(float a, float b) {
    return __builtin_bit_cast(v2h, __builtin_amdgcn_cvt_pkrtz(a, b));
}

// slot(k) within a row: fragment elem order for lane group lhi = k>>2 (k<16)
// elems 0-3 <-> k = lhi*4+j, elems 4-7 <-> k = 16+lhi*4+j
__device__ __forceinline__ int kslot(int k) {
    return (k < 16) ? ((k >> 2) * 8 + (k & 3)) : (((k - 16) >> 2) * 8 + 4 + ((k - 16) & 3));
}

// ---------------------------------------------------------------------------
// Prep: gather Y into x32-MFMA-fragment-ordered f16 tables (per 32-g block).
// A1buf: A-operand of G^T gemm (m=g, k=ksh). B2buf: B-operand of CO gemm
// (k=g, n=ksh), qw folded in.
// ---------------------------------------------------------------------------
__global__ void vg_prep(const float* __restrict__ Y, const float* __restrict__ qw,
                        f16* __restrict__ A1buf, f16* __restrict__ B2buf) {
    const int gb = blockIdx.x;
    const int lane = threadIdx.x & 63;
    const int lhi = lane >> 4, llo = lane & 15;
#pragma unroll
    for (int gh = 0; gh < 2; ++gh) {
        const int g = gb * 32 + gh * 16 + llo;
#pragma unroll
        for (int j = 0; j < 8; ++j) {
            const int k = (j < 4) ? (lhi * 4 + j) : (16 + lhi * 4 + (j - 4));
            const float v = (k < 25) ? Y[k * G_TOT + g] : 0.0f;
            A1buf[((gb * 2 + gh) * 64 + lane) * 8 + j] = (f16)v;
        }
    }
#pragma unroll
    for (int t = 0; t < 2; ++t) {
        const int k = t * 16 + llo;
#pragma unroll
        for (int j = 0; j < 8; ++j) {
            const int g = gb * 32 + ((j < 4) ? (lhi * 4 + j) : (16 + lhi * 4 + (j - 4)));
            const float v = (k < 25) ? Y[k * G_TOT + g] * qw[g] : 0.0f;
            B2buf[((gb * 2 + t) * 64 + lane) * 8 + j] = (f16)v;
        }
    }
}

// ---------------------------------------------------------------------------
// Main fused kernel: one block of 128 threads per (n, parity).
// Wave w = h (c-half) owns row tiles Rn = 2v+h exclusively and iterates ALL
// 63 g-blocks -> small per-wave register set (3+ waves/SIMD) and NO
// inter-wave reduction (waves write disjoint CO rows).
// MFMA1 (swapped, x32): D1[g][row] = sum_ksh Y[ksh][g] * h[row][ksh]
// cross in-register (v_cvt_pkrtz pack) -> A-fragment of MFMA2
// MFMA2 (x32): CO[row][ksh] += sum_g cr[row][g] * Yw[ksh][g]
// ---------------------------------------------------------------------------
template <bool USE_WS>
__global__ __launch_bounds__(128, 3)
void vg_main(const float* __restrict__ x1, const float* __restrict__ x2,
             const float* __restrict__ W1s, const float* __restrict__ W2s,
             const float* __restrict__ Wouts, const float* __restrict__ Y,
             const float* __restrict__ qw,
             const f16* __restrict__ A1buf, const f16* __restrict__ B2buf,
             float* __restrict__ out) {
    __shared__ __align__(16) char smem[15360];
    f16* hb = (f16*)smem;        // [2][96][HSTR] f16, fragment-contiguous (phase 0)
    float* cob = (float*)smem;   // [96][CSTR] f32 (epilogue; aliased, 12.7KB)

    const int bid = blockIdx.x;
    const int n = bid / 3, p = bid % 3;
    const int tid = threadIdx.x;
    const int h = tid >> 6;      // wave id == c-half owned
    const int lane = tid & 63;
    const int lhi = lane >> 4, llo = lane & 15;

    // ---- phase 0a: zero hb (padding slots must be 0)
    for (int i = tid; i < 3840; i += 128) ((float*)smem)[i] = 0.0f;
    __syncthreads();

    // ---- phase 0b: h[row=v*32+c][k] = sum_f x[f,v,k] * W[l_k,f,c], cast f16.
    {
        const int c = tid & 31, grp = tid >> 5;
        const float* x1n = x1 + n * 2400;
        const float* x2n = x2 + n * 2400;
        const float* W1p = W1s + p * 5120;
        const float* W2p = W2s + p * 5120;
        for (int vk = grp; vk < 75; vk += 4) {
            const int v = vk / 25, k = vk - v * 25;
            const int l = (k >= 16) ? 4 : (k >= 9) ? 3 : (k >= 4) ? 2 : (k >= 1) ? 1 : 0;
            const float* w1 = W1p + l * 1024 + c;
            const float* w2 = W2p + l * 1024 + c;
            float a1 = 0.0f, a2s = 0.0f;
#pragma unroll
            for (int f = 0; f < 32; ++f) {
                a1 += x1n[f * 75 + vk] * w1[f * 32];
                a2s += x2n[f * 75 + vk] * w2[f * 32];
            }
            const int row = v * 32 + c;
            const int sl = kslot(k);
            hb[row * HSTR + sl] = (f16)a1;
            hb[96 * HSTR + row * HSTR + sl] = (f16)a2s;
        }
    }
    __syncthreads();

    // ---- hoist this wave's h fragments: tiles Rn = 2*vc + h (6 x v8h = 24 VGPR)
    v8h hfr[2][3];
    {
        const f16* hfb = &hb[llo * HSTR + lhi * 8];
#pragma unroll
        for (int s = 0; s < 2; ++s)
#pragma unroll
            for (int vc = 0; vc < 3; ++vc)
                hfr[s][vc] = *(const v8h*)(hfb + (s * 96 + (2 * vc + h) * 16) * HSTR);
    }

    const v4f zero4 = {0.0f, 0.0f, 0.0f, 0.0f};
    v4f coacc[3][2];
#pragma unroll
    for (int vc = 0; vc < 3; ++vc)
#pragma unroll
        for (int t = 0; t < 2; ++t) coacc[vc][t] = zero4;

    union A2U { v2h p[4]; v8h v; };

    // ---- main loop: every wave walks ALL 63 g-blocks, reg-only inner body
    if constexpr (USE_WS) {
        const v8h* a1b = (const v8h*)A1buf;   // [gb][gh][lane] of v8h, 128 per gb
        const v8h* b2b = (const v8h*)B2buf;
        v8h a10 = a1b[lane];
        v8h a11 = a1b[64 + lane];
        v8h b20 = b2b[lane];
        v8h b21 = b2b[64 + lane];
        for (int gb = 0; gb < NGB32; ++gb) {
            const int gbn = (gb + 1 < NGB32) ? gb + 1 : gb;
            v8h a10n = a1b[gbn * 128 + lane];
            v8h a11n = a1b[gbn * 128 + 64 + lane];
            v8h b20n = b2b[gbn * 128 + lane];
            v8h b21n = b2b[gbn * 128 + 64 + lane];

            A2U a2u[3];
#pragma unroll
            for (int gh = 0; gh < 2; ++gh) {
                const v8h a1 = gh ? a11 : a10;
                v4f ag[2][3];
#pragma unroll
                for (int s = 0; s < 2; ++s)
#pragma unroll
                    for (int vc = 0; vc < 3; ++vc)
                        ag[s][vc] = __builtin_amdgcn_mfma_f32_16x16x32_f16(
                            a1, hfr[s][vc], zero4, 0, 0, 0);
#pragma unroll
                for (int jp = 0; jp < 2; ++jp) {
                    const int j0 = 2 * jp, j1 = 2 * jp + 1;
                    float cr0[3], cr1[3];
                    cr0[0] = ag[0][1][j0] * ag[1][2][j0] - ag[0][2][j0] * ag[1][1][j0];
                    cr0[1] = ag[0][2][j0] * ag[1][0][j0] - ag[0][0][j0] * ag[1][2][j0];
                    cr0[2] = ag[0][0][j0] * ag[1][1][j0] - ag[0][1][j0] * ag[1][0][j0];
                    cr1[0] = ag[0][1][j1] * ag[1][2][j1] - ag[0][2][j1] * ag[1][1][j1];
                    cr1[1] = ag[0][2][j1] * ag[1][0][j1] - ag[0][0][j1] * ag[1][2][j1];
                    cr1[2] = ag[0][0][j1] * ag[1][1][j1] - ag[0][1][j1] * ag[1][0][j1];
#pragma unroll
                    for (int c = 0; c < 3; ++c)
                        a2u[c].p[gh * 2 + jp] = pkrtz(cr0[c], cr1[c]);
                }
            }
#pragma unroll
            for (int vc = 0; vc < 3; ++vc) {
                coacc[vc][0] = __builtin_amdgcn_mfma_f32_16x16x32_f16(a2u[vc].v, b20, coacc[vc][0], 0, 0, 0);
                coacc[vc][1] = __builtin_amdgcn_mfma_f32_16x16x32_f16(a2u[vc].v, b21, coacc[vc][1], 0, 0, 0);
            }
            a10 = a10n; a11 = a11n; b20 = b20n; b21 = b21n;
        }
    } else {
        for (int gb = 0; gb < NGB32; ++gb) {
            v8h b20, b21;
#pragma unroll
            for (int j = 0; j < 8; ++j) {
                const int gg = gb * 32 + ((j < 4) ? (lhi * 4 + j) : (16 + lhi * 4 + (j - 4)));
                const float qg = qw[gg];
                b20[j] = (f16)(Y[llo * G_TOT + gg] * qg);
                const int k1 = 16 + llo;
                b21[j] = (f16)((k1 < 25) ? Y[k1 * G_TOT + gg] * qg : 0.0f);
            }
            A2U a2u[3];
#pragma unroll
            for (int gh = 0; gh < 2; ++gh) {
                v8h a1;
                const int g0 = gb * 32 + gh * 16 + llo;
#pragma unroll
                for (int j = 0; j < 8; ++j) {
                    const int k = (j < 4) ? (lhi * 4 + j) : (16 + lhi * 4 + (j - 4));
                    a1[j] = (f16)((k < 25) ? Y[k * G_TOT + g0] : 0.0f);
                }
                v4f ag[2][3];
#pragma unroll
                for (int s = 0; s < 2; ++s)
#pragma unroll
                    for (int vc = 0; vc < 3; ++vc)
                        ag[s][vc] = __builtin_amdgcn_mfma_f32_16x16x32_f16(
                            a1, hfr[s][vc], zero4, 0, 0, 0);
#pragma unroll
                for (int jp = 0; jp < 2; ++jp) {
                    const int j0 = 2 * jp, j1 = 2 * jp + 1;
                    float cr0[3], cr1[3];
                    cr0[0] = ag[0][1][j0] * ag[1][2][j0] - ag[0][2][j0] * ag[1][1][j0];
                    cr0[1] = ag[0][2][j0] * ag[1][0][j0] - ag[0][0][j0] * ag[1][2][j0];
                    cr0[2] = ag[0][0][j0] * ag[1][1][j0] - ag[0][1][j0] * ag[1][0][j0];
                    cr1[0] = ag[0][1][j1] * ag[1][2][j1] - ag[0][2][j1] * ag[1][1][j1];
                    cr1[1] = ag[0][2][j1] * ag[1][0][j1] - ag[0][0][j1] * ag[1][2][j1];
                    cr1[2] = ag[0][0][j1] * ag[1][1][j1] - ag[0][1][j1] * ag[1][0][j1];
#pragma unroll
                    for (int c = 0; c < 3; ++c)
                        a2u[c].p[gh * 2 + jp] = pkrtz(cr0[c], cr1[c]);
                }
            }
#pragma unroll
            for (int vc = 0; vc < 3; ++vc) {
                coacc[vc][0] = __builtin_amdgcn_mfma_f32_16x16x32_f16(a2u[vc].v, b20, coacc[vc][0], 0, 0, 0);
                coacc[vc][1] = __builtin_amdgcn_mfma_f32_16x16x32_f16(a2u[vc].v, b21, coacc[vc][1], 0, 0, 0);
            }
        }
    }

    // ---- write CO to LDS: waves own disjoint rows -> no reduction needed.
    // sync first: cob aliases hb and the other wave read hfr from hb earlier.
    __syncthreads();
#pragma unroll
    for (int vc = 0; vc < 3; ++vc)
#pragma unroll
        for (int t = 0; t < 2; ++t)
#pragma unroll
            for (int j = 0; j < 4; ++j) {
                const int row = (2 * vc + h) * 16 + lhi * 4 + j;
                cob[row * CSTR + t * 16 + llo] = coacc[vc][t][j];
            }
    __syncthreads();

    // ---- epilogue: out[n, p*32+b, v, k] = sum_a co[v*32+a][k] * Wout[p,l_k,a,b]
    const float* Wop = Wouts + p * 5120;
    float* outp = out + (n * 96 + p * 32) * 75;
    for (int idx = tid; idx < 300; idx += 128) {
        const int vk = idx % 75, q = idx / 75;
        const int v = vk / 25, k = vk - v * 25;
        const int l = (k >= 16) ? 4 : (k >= 9) ? 3 : (k >= 4) ? 2 : (k >= 1) ? 1 : 0;
        const float* w = Wop + l * 1024 + q * 8;
        float acc[8];
#pragma unroll
        for (int b = 0; b < 8; ++b) acc[b] = 0.0f;
        for (int a = 0; a < 32; ++a) {
            const float cv = cob[(v * 32 + a) * CSTR + k];
#pragma unroll
            for (int b = 0; b < 8; ++b) acc[b] += cv * w[a * 32 + b];
        }
#pragma unroll
        for (int b = 0; b < 8; ++b) outp[(q * 8 + b) * 75 + vk] = acc[b];
    }
}

extern "C" void kernel_launch(void* const* d_in, const int* in_sizes, int n_in,
                              void* d_out, int out_size, void* d_ws, size_t ws_size,
                              hipStream_t stream) {
    const float* x1 = (const float*)d_in[0];
    const float* x2 = (const float*)d_in[1];
    const float* W1s = (const float*)d_in[2];
    const float* W2s = (const float*)d_in[3];
    const float* Wouts = (const float*)d_in[4];
    const float* Y = (const float*)d_in[5];
    const float* qw = (const float*)d_in[6];
    float* out = (float*)d_out;

    f16* A1buf = (f16*)d_ws;
    f16* B2buf = (f16*)((char*)d_ws + 129024);

    if (ws_size >= 258048) {
        vg_prep<<<NGB32, 64, 0, stream>>>(Y, qw, A1buf, B2buf);
        vg_main<true><<<1536, 128, 0, stream>>>(x1, x2, W1s, W2s, Wouts, Y, qw,
                                                A1buf, B2buf, out);
    } else {
        vg_main<false><<<1536, 128, 0, stream>>>(x1, x2, W1s, W2s, Wouts, Y, qw,
                                                 nullptr, nullptr, out);
    }
}

// Round 8
// 106.895 us; speedup vs baseline: 1.2611x; 1.2611x over previous
//
#include <hip/hip_runtime.h>

#define G_TOT 2016
#define NGB32 63
#define HSTR 40   // hbuf row stride in f16 (80B): fragment-contiguous, 2-way banks
#define CSTR 33   // cob row stride (f32)

typedef _Float16 f16;
typedef __attribute__((ext_vector_type(2))) _Float16 v2h;
typedef __attribute__((ext_vector_type(8))) _Float16 v8h;
typedef __attribute__((ext_vector_type(4))) float v4f;

__device__ __forceinline__ v2h pkrtz(float a, float b) {
    return __builtin_bit_cast(v2h, __builtin_amdgcn_cvt_pkrtz(a, b));
}

// ---------------------------------------------------------------------------
// Prep: gather Y into x32-MFMA-fragment-ordered f16 tables (per 32-g block).
// ---------------------------------------------------------------------------
__global__ void vg_prep(const float* __restrict__ Y, const float* __restrict__ qw,
                        f16* __restrict__ A1buf, f16* __restrict__ B2buf) {
    const int gb = blockIdx.x;
    const int lane = threadIdx.x & 63;
    const int lhi = lane >> 4, llo = lane & 15;
#pragma unroll
    for (int gh = 0; gh < 2; ++gh) {
        const int g = gb * 32 + gh * 16 + llo;
#pragma unroll
        for (int j = 0; j < 8; ++j) {
            const int k = (j < 4) ? (lhi * 4 + j) : (16 + lhi * 4 + (j - 4));
            const float v = (k < 25) ? Y[k * G_TOT + g] : 0.0f;
            A1buf[((gb * 2 + gh) * 64 + lane) * 8 + j] = (f16)v;
        }
    }
#pragma unroll
    for (int t = 0; t < 2; ++t) {
        const int k = t * 16 + llo;
#pragma unroll
        for (int j = 0; j < 8; ++j) {
            const int g = gb * 32 + ((j < 4) ? (lhi * 4 + j) : (16 + lhi * 4 + (j - 4)));
            const float v = (k < 25) ? Y[k * G_TOT + g] * qw[g] : 0.0f;
            B2buf[((gb * 2 + t) * 64 + lane) * 8 + j] = (f16)v;
        }
    }
}

// ---------------------------------------------------------------------------
// Main fused kernel: 256 threads per (n, parity); waves = (h = c-half, q = g-half).
// Phase 0 channel mix is MFMA-based (waves 0,1 do s=0,1): h[vk][c] is a K=32
// GEMM; l-selected via static ternaries; writes hb fragment layout.
// Main loop: wave (h,q) owns row tiles Rn=2vc+h, g-blocks gb = q,q+2,...
// MFMA1 (swapped): D1[g][row]; cross in-register (pkrtz) -> A-frag of MFMA2;
// MFMA2: CO[row][k] accumulate. 2-way q-reduce in LDS, then epilogue.
// ---------------------------------------------------------------------------
template <bool USE_WS>
__global__ __launch_bounds__(256, 3)
void vg_main(const float* __restrict__ x1, const float* __restrict__ x2,
             const float* __restrict__ W1s, const float* __restrict__ W2s,
             const float* __restrict__ Wouts, const float* __restrict__ Y,
             const float* __restrict__ qw,
             const f16* __restrict__ A1buf, const f16* __restrict__ B2buf,
             float* __restrict__ out) {
    __shared__ __align__(16) char smem[15360];
    f16* hb = (f16*)smem;        // [2][96][HSTR] f16, fragment layout (phase 0)
    float* cob = (float*)smem;   // [96][CSTR] f32 (reduce/epilogue; aliased)

    const int bid = blockIdx.x;
    const int n = bid / 3, p = bid % 3;
    const int tid = threadIdx.x;
    const int wid = tid >> 6;
    const int h = wid & 1;       // c-half owned
    const int q = wid >> 1;      // g-split
    const int lane = tid & 63;
    const int lhi = lane >> 4, llo = lane & 15;

    const v4f zero4 = {0.0f, 0.0f, 0.0f, 0.0f};

    // ---- phase 0a: zero hb (padding slots must be 0)
    for (int i = tid; i < 3840; i += 256) ((float*)smem)[i] = 0.0f;
    __syncthreads();

    // ---- phase 0b (MFMA): wave s=wid in {0,1} computes h_s[row][k] fragments.
    // h[vk][c] = sum_f x[f][vk] * W_l(vk)[f][c]; one 16x16x32 MFMA per (vt,l,ct).
    if (wid < 2) {
        const int s = wid;
        const float* xs = (s ? x2 : x1) + n * 2400;
        const float* Wp = (s ? W2s : W1s) + p * 5120;
        // B-frags: W_l[f][c-tile]
        v8h bf[5][2];
#pragma unroll
        for (int l = 0; l < 5; ++l)
#pragma unroll
            for (int ct = 0; ct < 2; ++ct)
#pragma unroll
                for (int j = 0; j < 8; ++j) {
                    const int f = (j < 4) ? (lhi * 4 + j) : (16 + lhi * 4 + (j - 4));
                    bf[l][ct][j] = (f16)Wp[l * 1024 + f * 32 + ct * 16 + llo];
                }
        f16* hbs = hb + s * 96 * HSTR;
#pragma unroll
        for (int vt = 0; vt < 5; ++vt) {
            // A-frag: x[f][vk], m = vk = vt*16+llo
            v8h af;
            const int vkb = vt * 16 + llo;
#pragma unroll
            for (int j = 0; j < 8; ++j) {
                const int f = (j < 4) ? (lhi * 4 + j) : (16 + lhi * 4 + (j - 4));
                af[j] = (vkb < 75) ? (f16)xs[f * 75 + vkb] : (f16)0.0f;
            }
            v4f D[5][2];
#pragma unroll
            for (int l = 0; l < 5; ++l)
#pragma unroll
                for (int ct = 0; ct < 2; ++ct)
                    D[l][ct] = __builtin_amdgcn_mfma_f32_16x16x32_f16(af, bf[l][ct], zero4, 0, 0, 0);
            // D[m = vt*16+lhi*4+j][c = ct*16+llo] -> select l by k, scatter to hb
#pragma unroll
            for (int ct = 0; ct < 2; ++ct)
#pragma unroll
                for (int j = 0; j < 4; ++j) {
                    const int vk = vt * 16 + lhi * 4 + j;   // runtime (lhi)
                    if (vk < 75) {
                        const int v = (vk >= 50) ? 2 : ((vk >= 25) ? 1 : 0);
                        const int k = vk - v * 25;
                        const float val = (k < 1) ? D[0][ct][j]
                                        : (k < 4) ? D[1][ct][j]
                                        : (k < 9) ? D[2][ct][j]
                                        : (k < 16) ? D[3][ct][j]
                                        : D[4][ct][j];
                        const int ks = (k < 16) ? ((k >> 2) * 8 + (k & 3))
                                               : (((k - 16) >> 2) * 8 + 4 + ((k - 16) & 3));
                        hbs[(v * 32 + ct * 16 + llo) * HSTR + ks] = (f16)val;
                    }
                }
        }
    }
    __syncthreads();

    // ---- hoist this wave's h fragments: tiles Rn = 2*vc + h (6 x v8h = 24 VGPR)
    v8h hfr[2][3];
    {
        const f16* hfb = &hb[llo * HSTR + lhi * 8];
#pragma unroll
        for (int s = 0; s < 2; ++s)
#pragma unroll
            for (int vc = 0; vc < 3; ++vc)
                hfr[s][vc] = *(const v8h*)(hfb + (s * 96 + (2 * vc + h) * 16) * HSTR);
    }

    v4f coacc[3][2];
#pragma unroll
    for (int vc = 0; vc < 3; ++vc)
#pragma unroll
        for (int t = 0; t < 2; ++t) coacc[vc][t] = zero4;

    union A2U { v2h p[4]; v8h v; };

    // ---- main loop: wave (h,q) walks gb = q, q+2, ... (reg-only inner body)
    if constexpr (USE_WS) {
        const v8h* a1b = (const v8h*)A1buf;   // [gb][gh][lane] of v8h, 128 per gb
        const v8h* b2b = (const v8h*)B2buf;
        v8h a10 = a1b[q * 128 + lane];
        v8h a11 = a1b[q * 128 + 64 + lane];
        v8h b20 = b2b[q * 128 + lane];
        v8h b21 = b2b[q * 128 + 64 + lane];
        for (int gb = q; gb < NGB32; gb += 2) {
            const int gbn = (gb + 2 < NGB32) ? gb + 2 : gb;
            v8h a10n = a1b[gbn * 128 + lane];
            v8h a11n = a1b[gbn * 128 + 64 + lane];
            v8h b20n = b2b[gbn * 128 + lane];
            v8h b21n = b2b[gbn * 128 + 64 + lane];

            A2U a2u[3];
#pragma unroll
            for (int gh = 0; gh < 2; ++gh) {
                const v8h a1 = gh ? a11 : a10;
                v4f ag[2][3];
#pragma unroll
                for (int s = 0; s < 2; ++s)
#pragma unroll
                    for (int vc = 0; vc < 3; ++vc)
                        ag[s][vc] = __builtin_amdgcn_mfma_f32_16x16x32_f16(
                            a1, hfr[s][vc], zero4, 0, 0, 0);
#pragma unroll
                for (int jp = 0; jp < 2; ++jp) {
                    const int j0 = 2 * jp, j1 = 2 * jp + 1;
                    float cr0[3], cr1[3];
                    cr0[0] = ag[0][1][j0] * ag[1][2][j0] - ag[0][2][j0] * ag[1][1][j0];
                    cr0[1] = ag[0][2][j0] * ag[1][0][j0] - ag[0][0][j0] * ag[1][2][j0];
                    cr0[2] = ag[0][0][j0] * ag[1][1][j0] - ag[0][1][j0] * ag[1][0][j0];
                    cr1[0] = ag[0][1][j1] * ag[1][2][j1] - ag[0][2][j1] * ag[1][1][j1];
                    cr1[1] = ag[0][2][j1] * ag[1][0][j1] - ag[0][0][j1] * ag[1][2][j1];
                    cr1[2] = ag[0][0][j1] * ag[1][1][j1] - ag[0][1][j1] * ag[1][0][j1];
#pragma unroll
                    for (int c = 0; c < 3; ++c)
                        a2u[c].p[gh * 2 + jp] = pkrtz(cr0[c], cr1[c]);
                }
            }
#pragma unroll
            for (int vc = 0; vc < 3; ++vc) {
                coacc[vc][0] = __builtin_amdgcn_mfma_f32_16x16x32_f16(a2u[vc].v, b20, coacc[vc][0], 0, 0, 0);
                coacc[vc][1] = __builtin_amdgcn_mfma_f32_16x16x32_f16(a2u[vc].v, b21, coacc[vc][1], 0, 0, 0);
            }
            a10 = a10n; a11 = a11n; b20 = b20n; b21 = b21n;
        }
    } else {
        for (int gb = q; gb < NGB32; gb += 2) {
            v8h b20, b21;
#pragma unroll
            for (int j = 0; j < 8; ++j) {
                const int gg = gb * 32 + ((j < 4) ? (lhi * 4 + j) : (16 + lhi * 4 + (j - 4)));
                const float qg = qw[gg];
                b20[j] = (f16)(Y[llo * G_TOT + gg] * qg);
                const int k1 = 16 + llo;
                b21[j] = (f16)((k1 < 25) ? Y[k1 * G_TOT + gg] * qg : 0.0f);
            }
            A2U a2u[3];
#pragma unroll
            for (int gh = 0; gh < 2; ++gh) {
                v8h a1;
                const int g0 = gb * 32 + gh * 16 + llo;
#pragma unroll
                for (int j = 0; j < 8; ++j) {
                    const int k = (j < 4) ? (lhi * 4 + j) : (16 + lhi * 4 + (j - 4));
                    a1[j] = (f16)((k < 25) ? Y[k * G_TOT + g0] : 0.0f);
                }
                v4f ag[2][3];
#pragma unroll
                for (int s = 0; s < 2; ++s)
#pragma unroll
                    for (int vc = 0; vc < 3; ++vc)
                        ag[s][vc] = __builtin_amdgcn_mfma_f32_16x16x32_f16(
                            a1, hfr[s][vc], zero4, 0, 0, 0);
#pragma unroll
                for (int jp = 0; jp < 2; ++jp) {
                    const int j0 = 2 * jp, j1 = 2 * jp + 1;
                    float cr0[3], cr1[3];
                    cr0[0] = ag[0][1][j0] * ag[1][2][j0] - ag[0][2][j0] * ag[1][1][j0];
                    cr0[1] = ag[0][2][j0] * ag[1][0][j0] - ag[0][0][j0] * ag[1][2][j0];
                    cr0[2] = ag[0][0][j0] * ag[1][1][j0] - ag[0][1][j0] * ag[1][0][j0];
                    cr1[0] = ag[0][1][j1] * ag[1][2][j1] - ag[0][2][j1] * ag[1][1][j1];
                    cr1[1] = ag[0][2][j1] * ag[1][0][j1] - ag[0][0][j1] * ag[1][2][j1];
                    cr1[2] = ag[0][0][j1] * ag[1][1][j1] - ag[0][1][j1] * ag[1][0][j1];
#pragma unroll
                    for (int c = 0; c < 3; ++c)
                        a2u[c].p[gh * 2 + jp] = pkrtz(cr0[c], cr1[c]);
                }
            }
#pragma unroll
            for (int vc = 0; vc < 3; ++vc) {
                coacc[vc][0] = __builtin_amdgcn_mfma_f32_16x16x32_f16(a2u[vc].v, b20, coacc[vc][0], 0, 0, 0);
                coacc[vc][1] = __builtin_amdgcn_mfma_f32_16x16x32_f16(a2u[vc].v, b21, coacc[vc][1], 0, 0, 0);
            }
        }
    }

    // ---- CO: q=0 writes, q=1 accumulates (waves own disjoint rows across h)
    __syncthreads();
    if (q == 0) {
#pragma unroll
        for (int vc = 0; vc < 3; ++vc)
#pragma unroll
            for (int t = 0; t < 2; ++t)
#pragma unroll
                for (int j = 0; j < 4; ++j) {
                    const int row = (2 * vc + h) * 16 + lhi * 4 + j;
                    cob[row * CSTR + t * 16 + llo] = coacc[vc][t][j];
                }
    }
    __syncthreads();
    if (q == 1) {
#pragma unroll
        for (int vc = 0; vc < 3; ++vc)
#pragma unroll
            for (int t = 0; t < 2; ++t)
#pragma unroll
                for (int j = 0; j < 4; ++j) {
                    const int row = (2 * vc + h) * 16 + lhi * 4 + j;
                    cob[row * CSTR + t * 16 + llo] += coacc[vc][t][j];
                }
    }
    __syncthreads();

    // ---- epilogue: out[n, p*32+b, v, k] = sum_a co[v*32+a][k] * Wout[p,l_k,a,b]
    const float* Wop = Wouts + p * 5120;
    float* outp = out + (n * 96 + p * 32) * 75;
    for (int idx = tid; idx < 300; idx += 256) {
        const int vk = idx % 75, qq = idx / 75;
        const int v = vk / 25, k = vk - v * 25;
        const int l = (k >= 16) ? 4 : (k >= 9) ? 3 : (k >= 4) ? 2 : (k >= 1) ? 1 : 0;
        const float* w = Wop + l * 1024 + qq * 8;
        float acc[8];
#pragma unroll
        for (int b = 0; b < 8; ++b) acc[b] = 0.0f;
        for (int a = 0; a < 32; ++a) {
            const float cv = cob[(v * 32 + a) * CSTR + k];
#pragma unroll
            for (int b = 0; b < 8; ++b) acc[b] += cv * w[a * 32 + b];
        }
#pragma unroll
        for (int b = 0; b < 8; ++b) outp[(qq * 8 + b) * 75 + vk] = acc[b];
    }
}

extern "C" void kernel_launch(void* const* d_in, const int* in_sizes, int n_in,
                              void* d_out, int out_size, void* d_ws, size_t ws_size,
                              hipStream_t stream) {
    const float* x1 = (const float*)d_in[0];
    const float* x2 = (const float*)d_in[1];
    const float* W1s = (const float*)d_in[2];
    const float* W2s = (const float*)d_in[3];
    const float* Wouts = (const float*)d_in[4];
    const float* Y = (const float*)d_in[5];
    const float* qw = (const float*)d_in[6];
    float* out = (float*)d_out;

    f16* A1buf = (f16*)d_ws;
    f16* B2buf = (f16*)((char*)d_ws + 129024);

    if (ws_size >= 258048) {
        vg_prep<<<NGB32, 64, 0, stream>>>(Y, qw, A1buf, B2buf);
        vg_main<true><<<1536, 256, 0, stream>>>(x1, x2, W1s, W2s, Wouts, Y, qw,
                                                A1buf, B2buf, out);
    } else {
        vg_main<false><<<1536, 256, 0, stream>>>(x1, x2, W1s, W2s, Wouts, Y, qw,
                                                 nullptr, nullptr, out);
    }
}

// Round 9
// 81.030 us; speedup vs baseline: 1.6636x; 1.3192x over previous
//
#include <hip/hip_runtime.h>

#define G_TOT 2016
#define NGB32 63
#define HSTR 40   // hbuf row stride in f16 (80B): fragment-contiguous, 2-way banks
#define CSTR 33   // cob row stride (f32)

typedef _Float16 f16;
typedef __attribute__((ext_vector_type(2))) _Float16 v2h;
typedef __attribute__((ext_vector_type(8))) _Float16 v8h;
typedef __attribute__((ext_vector_type(4))) float v4f;

__device__ __forceinline__ v2h pkrtz(float a, float b) {
    return __builtin_bit_cast(v2h, __builtin_amdgcn_cvt_pkrtz(a, b));
}

// ---------------------------------------------------------------------------
// Prep: gather Y into x32-MFMA-fragment-ordered f16 tables (per 32-g block).
// ---------------------------------------------------------------------------
__global__ void vg_prep(const float* __restrict__ Y, const float* __restrict__ qw,
                        f16* __restrict__ A1buf, f16* __restrict__ B2buf) {
    const int gb = blockIdx.x;
    const int lane = threadIdx.x & 63;
    const int lhi = lane >> 4, llo = lane & 15;
#pragma unroll
    for (int gh = 0; gh < 2; ++gh) {
        const int g = gb * 32 + gh * 16 + llo;
#pragma unroll
        for (int j = 0; j < 8; ++j) {
            const int k = (j < 4) ? (lhi * 4 + j) : (16 + lhi * 4 + (j - 4));
            const float v = (k < 25) ? Y[k * G_TOT + g] : 0.0f;
            A1buf[((gb * 2 + gh) * 64 + lane) * 8 + j] = (f16)v;
        }
    }
#pragma unroll
    for (int t = 0; t < 2; ++t) {
        const int k = t * 16 + llo;
#pragma unroll
        for (int j = 0; j < 8; ++j) {
            const int g = gb * 32 + ((j < 4) ? (lhi * 4 + j) : (16 + lhi * 4 + (j - 4)));
            const float v = (k < 25) ? Y[k * G_TOT + g] * qw[g] : 0.0f;
            B2buf[((gb * 2 + t) * 64 + lane) * 8 + j] = (f16)v;
        }
    }
}

// ---------------------------------------------------------------------------
// Main fused kernel: 256 threads per (n, parity); waves = (h = c-half, q = g-half).
// Phase 0 channel mix is MFMA-based. Main loop per wave: MFMA1 -> pkrtz ->
// PACKED-f16 cross (v_pk_mul/v_pk_fma) -> MFMA2. Pointer-bump ws addressing.
// ---------------------------------------------------------------------------
template <bool USE_WS>
__global__ __launch_bounds__(256, 3)
void vg_main(const float* __restrict__ x1, const float* __restrict__ x2,
             const float* __restrict__ W1s, const float* __restrict__ W2s,
             const float* __restrict__ Wouts, const float* __restrict__ Y,
             const float* __restrict__ qw,
             const f16* __restrict__ A1buf, const f16* __restrict__ B2buf,
             float* __restrict__ out) {
    __shared__ __align__(16) char smem[15360];
    f16* hb = (f16*)smem;        // [2][96][HSTR] f16, fragment layout (phase 0)
    float* cob = (float*)smem;   // [96][CSTR] f32 (reduce/epilogue; aliased)

    const int bid = blockIdx.x;
    const int n = bid / 3, p = bid % 3;
    const int tid = threadIdx.x;
    const int wid = tid >> 6;
    const int h = wid & 1;       // c-half owned
    const int q = wid >> 1;      // g-split
    const int lane = tid & 63;
    const int lhi = lane >> 4, llo = lane & 15;

    const v4f zero4 = {0.0f, 0.0f, 0.0f, 0.0f};

    // ---- phase 0a: zero hb (padding slots must be 0)
    for (int i = tid; i < 3840; i += 256) ((float*)smem)[i] = 0.0f;
    __syncthreads();

    // ---- phase 0b (MFMA): wave s=wid in {0,1} computes h_s[row][k] fragments.
    if (wid < 2) {
        const int s = wid;
        const float* xs = (s ? x2 : x1) + n * 2400;
        const float* Wp = (s ? W2s : W1s) + p * 5120;
        v8h bf[5][2];
#pragma unroll
        for (int l = 0; l < 5; ++l)
#pragma unroll
            for (int ct = 0; ct < 2; ++ct)
#pragma unroll
                for (int j = 0; j < 8; ++j) {
                    const int f = (j < 4) ? (lhi * 4 + j) : (16 + lhi * 4 + (j - 4));
                    bf[l][ct][j] = (f16)Wp[l * 1024 + f * 32 + ct * 16 + llo];
                }
        f16* hbs = hb + s * 96 * HSTR;
#pragma unroll
        for (int vt = 0; vt < 5; ++vt) {
            v8h af;
            const int vkb = vt * 16 + llo;
#pragma unroll
            for (int j = 0; j < 8; ++j) {
                const int f = (j < 4) ? (lhi * 4 + j) : (16 + lhi * 4 + (j - 4));
                af[j] = (vkb < 75) ? (f16)xs[f * 75 + vkb] : (f16)0.0f;
            }
            v4f D[5][2];
#pragma unroll
            for (int l = 0; l < 5; ++l)
#pragma unroll
                for (int ct = 0; ct < 2; ++ct)
                    D[l][ct] = __builtin_amdgcn_mfma_f32_16x16x32_f16(af, bf[l][ct], zero4, 0, 0, 0);
#pragma unroll
            for (int ct = 0; ct < 2; ++ct)
#pragma unroll
                for (int j = 0; j < 4; ++j) {
                    const int vk = vt * 16 + lhi * 4 + j;
                    if (vk < 75) {
                        const int v = (vk >= 50) ? 2 : ((vk >= 25) ? 1 : 0);
                        const int k = vk - v * 25;
                        const float val = (k < 1) ? D[0][ct][j]
                                        : (k < 4) ? D[1][ct][j]
                                        : (k < 9) ? D[2][ct][j]
                                        : (k < 16) ? D[3][ct][j]
                                        : D[4][ct][j];
                        const int ks = (k < 16) ? ((k >> 2) * 8 + (k & 3))
                                               : (((k - 16) >> 2) * 8 + 4 + ((k - 16) & 3));
                        hbs[(v * 32 + ct * 16 + llo) * HSTR + ks] = (f16)val;
                    }
                }
        }
    }
    __syncthreads();

    // ---- hoist this wave's h fragments: tiles Rn = 2*vc + h (6 x v8h = 24 VGPR)
    v8h hfr[2][3];
    {
        const f16* hfb = &hb[llo * HSTR + lhi * 8];
#pragma unroll
        for (int s = 0; s < 2; ++s)
#pragma unroll
            for (int vc = 0; vc < 3; ++vc)
                hfr[s][vc] = *(const v8h*)(hfb + (s * 96 + (2 * vc + h) * 16) * HSTR);
    }

    v4f coacc[3][2];
#pragma unroll
    for (int vc = 0; vc < 3; ++vc)
#pragma unroll
        for (int t = 0; t < 2; ++t) coacc[vc][t] = zero4;

    union A2U { v2h p[4]; v8h v; };

    // packed-f16 cross for one gh: converts ag -> f16 pairs, cross in pk ops.
    // a2u[c].p[gh*2+jp] covers frag elems {gh*4+2jp, gh*4+2jp+1} = g offsets.
    auto cross_gh = [&](const v4f (&ag)[2][3], A2U (&a2u)[3], int gh) {
        v2h g1[3][2], g2[3][2];
#pragma unroll
        for (int vc = 0; vc < 3; ++vc) {
            g1[vc][0] = pkrtz(ag[0][vc][0], ag[0][vc][1]);
            g1[vc][1] = pkrtz(ag[0][vc][2], ag[0][vc][3]);
            g2[vc][0] = pkrtz(ag[1][vc][0], ag[1][vc][1]);
            g2[vc][1] = pkrtz(ag[1][vc][2], ag[1][vc][3]);
        }
#pragma unroll
        for (int jp = 0; jp < 2; ++jp) {
            a2u[0].p[gh * 2 + jp] = g1[1][jp] * g2[2][jp] - g1[2][jp] * g2[1][jp];
            a2u[1].p[gh * 2 + jp] = g1[2][jp] * g2[0][jp] - g1[0][jp] * g2[2][jp];
            a2u[2].p[gh * 2 + jp] = g1[0][jp] * g2[1][jp] - g1[1][jp] * g2[0][jp];
        }
    };

    // ---- main loop: wave (h,q) walks gb = q, q+2, ... (reg-only inner body)
    if constexpr (USE_WS) {
        const v8h* pa = (const v8h*)A1buf + q * 128 + lane;   // bump by 256/iter
        const v8h* pb = (const v8h*)B2buf + q * 128 + lane;
        const int iters = (NGB32 - q + 1) >> 1;               // q=0:32, q=1:31
        v8h a10 = pa[0], a11 = pa[64];
        v8h b20 = pb[0], b21 = pb[64];
        for (int it = 0; it < iters; ++it) {
            const bool last = (it + 1 >= iters);
            const v8h* pan = last ? pa : pa + 256;
            const v8h* pbn = last ? pb : pb + 256;
            v8h a10n = pan[0], a11n = pan[64];
            v8h b20n = pbn[0], b21n = pbn[64];
            pa = pan; pb = pbn;

            A2U a2u[3];
#pragma unroll
            for (int gh = 0; gh < 2; ++gh) {
                const v8h a1 = gh ? a11 : a10;
                v4f ag[2][3];
#pragma unroll
                for (int s = 0; s < 2; ++s)
#pragma unroll
                    for (int vc = 0; vc < 3; ++vc)
                        ag[s][vc] = __builtin_amdgcn_mfma_f32_16x16x32_f16(
                            a1, hfr[s][vc], zero4, 0, 0, 0);
                cross_gh(ag, a2u, gh);
            }
#pragma unroll
            for (int vc = 0; vc < 3; ++vc) {
                coacc[vc][0] = __builtin_amdgcn_mfma_f32_16x16x32_f16(a2u[vc].v, b20, coacc[vc][0], 0, 0, 0);
                coacc[vc][1] = __builtin_amdgcn_mfma_f32_16x16x32_f16(a2u[vc].v, b21, coacc[vc][1], 0, 0, 0);
            }
            a10 = a10n; a11 = a11n; b20 = b20n; b21 = b21n;
        }
    } else {
        for (int gb = q; gb < NGB32; gb += 2) {
            v8h b20, b21;
#pragma unroll
            for (int j = 0; j < 8; ++j) {
                const int gg = gb * 32 + ((j < 4) ? (lhi * 4 + j) : (16 + lhi * 4 + (j - 4)));
                const float qg = qw[gg];
                b20[j] = (f16)(Y[llo * G_TOT + gg] * qg);
                const int k1 = 16 + llo;
                b21[j] = (f16)((k1 < 25) ? Y[k1 * G_TOT + gg] * qg : 0.0f);
            }
            A2U a2u[3];
#pragma unroll
            for (int gh = 0; gh < 2; ++gh) {
                v8h a1;
                const int g0 = gb * 32 + gh * 16 + llo;
#pragma unroll
                for (int j = 0; j < 8; ++j) {
                    const int k = (j < 4) ? (lhi * 4 + j) : (16 + lhi * 4 + (j - 4));
                    a1[j] = (f16)((k < 25) ? Y[k * G_TOT + g0] : 0.0f);
                }
                v4f ag[2][3];
#pragma unroll
                for (int s = 0; s < 2; ++s)
#pragma unroll
                    for (int vc = 0; vc < 3; ++vc)
                        ag[s][vc] = __builtin_amdgcn_mfma_f32_16x16x32_f16(
                            a1, hfr[s][vc], zero4, 0, 0, 0);
                cross_gh(ag, a2u, gh);
            }
#pragma unroll
            for (int vc = 0; vc < 3; ++vc) {
                coacc[vc][0] = __builtin_amdgcn_mfma_f32_16x16x32_f16(a2u[vc].v, b20, coacc[vc][0], 0, 0, 0);
                coacc[vc][1] = __builtin_amdgcn_mfma_f32_16x16x32_f16(a2u[vc].v, b21, coacc[vc][1], 0, 0, 0);
            }
        }
    }

    // ---- CO: q=0 writes, q=1 accumulates (waves own disjoint rows across h)
    __syncthreads();
    if (q == 0) {
#pragma unroll
        for (int vc = 0; vc < 3; ++vc)
#pragma unroll
            for (int t = 0; t < 2; ++t)
#pragma unroll
                for (int j = 0; j < 4; ++j) {
                    const int row = (2 * vc + h) * 16 + lhi * 4 + j;
                    cob[row * CSTR + t * 16 + llo] = coacc[vc][t][j];
                }
    }
    __syncthreads();
    if (q == 1) {
#pragma unroll
        for (int vc = 0; vc < 3; ++vc)
#pragma unroll
            for (int t = 0; t < 2; ++t)
#pragma unroll
                for (int j = 0; j < 4; ++j) {
                    const int row = (2 * vc + h) * 16 + lhi * 4 + j;
                    cob[row * CSTR + t * 16 + llo] += coacc[vc][t][j];
                }
    }
    __syncthreads();

    // ---- epilogue: out[n, p*32+b, v, k] = sum_a co[v*32+a][k] * Wout[p,l_k,a,b]
    const float* Wop = Wouts + p * 5120;
    float* outp = out + (n * 96 + p * 32) * 75;
    for (int idx = tid; idx < 300; idx += 256) {
        const int vk = idx % 75, qq = idx / 75;
        const int v = vk / 25, k = vk - v * 25;
        const int l = (k >= 16) ? 4 : (k >= 9) ? 3 : (k >= 4) ? 2 : (k >= 1) ? 1 : 0;
        const float* w = Wop + l * 1024 + qq * 8;
        float acc[8];
#pragma unroll
        for (int b = 0; b < 8; ++b) acc[b] = 0.0f;
        for (int a = 0; a < 32; ++a) {
            const float cv = cob[(v * 32 + a) * CSTR + k];
#pragma unroll
            for (int b = 0; b < 8; ++b) acc[b] += cv * w[a * 32 + b];
        }
#pragma unroll
        for (int b = 0; b < 8; ++b) outp[(qq * 8 + b) * 75 + vk] = acc[b];
    }
}

extern "C" void kernel_launch(void* const* d_in, const int* in_sizes, int n_in,
                              void* d_out, int out_size, void* d_ws, size_t ws_size,
                              hipStream_t stream) {
    const float* x1 = (const float*)d_in[0];
    const float* x2 = (const float*)d_in[1];
    const float* W1s = (const float*)d_in[2];
    const float* W2s = (const float*)d_in[3];
    const float* Wouts = (const float*)d_in[4];
    const float* Y = (const float*)d_in[5];
    const float* qw = (const float*)d_in[6];
    float* out = (float*)d_out;

    f16* A1buf = (f16*)d_ws;
    f16* B2buf = (f16*)((char*)d_ws + 129024);

    if (ws_size >= 258048) {
        vg_prep<<<NGB32, 64, 0, stream>>>(Y, qw, A1buf, B2buf);
        vg_main<true><<<1536, 256, 0, stream>>>(x1, x2, W1s, W2s, Wouts, Y, qw,
                                                A1buf, B2buf, out);
    } else {
        vg_main<false><<<1536, 256, 0, stream>>>(x1, x2, W1s, W2s, Wouts, Y, qw,
                                                 nullptr, nullptr, out);
    }
}

// Round 10
// 77.765 us; speedup vs baseline: 1.7334x; 1.0420x over previous
//
#include <hip/hip_runtime.h>

#define G_TOT 2016
#define NGB32 63
#define HSTR 40   // hbuf row stride in f16 (80B): fragment-contiguous, 2-way banks
#define CSTR 33   // cob row stride (f32)

typedef _Float16 f16;
typedef __attribute__((ext_vector_type(2))) _Float16 v2h;
typedef __attribute__((ext_vector_type(8))) _Float16 v8h;
typedef __attribute__((ext_vector_type(4))) float v4f;

__device__ __forceinline__ v2h pkrtz(float a, float b) {
    return __builtin_bit_cast(v2h, __builtin_amdgcn_cvt_pkrtz(a, b));
}

// ---------------------------------------------------------------------------
// Prep: gather Y into x32-MFMA-fragment-ordered f16 tables (per 32-g block).
// ---------------------------------------------------------------------------
__global__ void vg_prep(const float* __restrict__ Y, const float* __restrict__ qw,
                        f16* __restrict__ A1buf, f16* __restrict__ B2buf) {
    const int gb = blockIdx.x;
    const int lane = threadIdx.x & 63;
    const int lhi = lane >> 4, llo = lane & 15;
#pragma unroll
    for (int gh = 0; gh < 2; ++gh) {
        const int g = gb * 32 + gh * 16 + llo;
#pragma unroll
        for (int j = 0; j < 8; ++j) {
            const int k = (j < 4) ? (lhi * 4 + j) : (16 + lhi * 4 + (j - 4));
            const float v = (k < 25) ? Y[k * G_TOT + g] : 0.0f;
            A1buf[((gb * 2 + gh) * 64 + lane) * 8 + j] = (f16)v;
        }
    }
#pragma unroll
    for (int t = 0; t < 2; ++t) {
        const int k = t * 16 + llo;
#pragma unroll
        for (int j = 0; j < 8; ++j) {
            const int g = gb * 32 + ((j < 4) ? (lhi * 4 + j) : (16 + lhi * 4 + (j - 4)));
            const float v = (k < 25) ? Y[k * G_TOT + g] * qw[g] : 0.0f;
            B2buf[((gb * 2 + t) * 64 + lane) * 8 + j] = (f16)v;
        }
    }
}

// ---------------------------------------------------------------------------
// Main fused kernel: 256 threads per (n, parity); waves = (h = c-half, q = g-half).
// Phase 0b: all 4 waves, wave (s=wid&1, ct=wid>>1) does a quarter of the mix.
// Main loop: unroll-2 ping-pong register pipeline (loads for body i+2 issued
// at end of body i -> ~1.5-body prefetch distance, no rotation movs).
// MFMA1 -> pkrtz -> packed-f16 cross -> MFMA2.
// ---------------------------------------------------------------------------
template <bool USE_WS>
__global__ __launch_bounds__(256, 3)
void vg_main(const float* __restrict__ x1, const float* __restrict__ x2,
             const float* __restrict__ W1s, const float* __restrict__ W2s,
             const float* __restrict__ Wouts, const float* __restrict__ Y,
             const float* __restrict__ qw,
             const f16* __restrict__ A1buf, const f16* __restrict__ B2buf,
             float* __restrict__ out) {
    __shared__ __align__(16) char smem[15360];
    f16* hb = (f16*)smem;        // [2][96][HSTR] f16, fragment layout (phase 0)
    float* cob = (float*)smem;   // [96][CSTR] f32 (reduce/epilogue; aliased)

    const int bid = blockIdx.x;
    const int n = bid / 3, p = bid % 3;
    const int tid = threadIdx.x;
    const int wid = tid >> 6;
    const int h = wid & 1;       // c-half owned (main loop)
    const int q = wid >> 1;      // g-split (main loop)
    const int lane = tid & 63;
    const int lhi = lane >> 4, llo = lane & 15;

    const v4f zero4 = {0.0f, 0.0f, 0.0f, 0.0f};

    // ---- phase 0a: zero hb (padding slots must be 0)
    for (int i = tid; i < 3840; i += 256) ((float*)smem)[i] = 0.0f;
    __syncthreads();

    // ---- phase 0b (MFMA, all 4 waves): wave (s, ct) computes its quarter.
    {
        const int s = wid & 1, ct = wid >> 1;
        const float* xs = (s ? x2 : x1) + n * 2400;
        const float* Wp = (s ? W2s : W1s) + p * 5120;
        v8h bf[5];
#pragma unroll
        for (int l = 0; l < 5; ++l)
#pragma unroll
            for (int j = 0; j < 8; ++j) {
                const int f = (j < 4) ? (lhi * 4 + j) : (16 + lhi * 4 + (j - 4));
                bf[l][j] = (f16)Wp[l * 1024 + f * 32 + ct * 16 + llo];
            }
        f16* hbs = hb + s * 96 * HSTR;
#pragma unroll
        for (int vt = 0; vt < 5; ++vt) {
            v8h af;
            const int vkb = vt * 16 + llo;
#pragma unroll
            for (int j = 0; j < 8; ++j) {
                const int f = (j < 4) ? (lhi * 4 + j) : (16 + lhi * 4 + (j - 4));
                af[j] = (vkb < 75) ? (f16)xs[f * 75 + vkb] : (f16)0.0f;
            }
            v4f D[5];
#pragma unroll
            for (int l = 0; l < 5; ++l)
                D[l] = __builtin_amdgcn_mfma_f32_16x16x32_f16(af, bf[l], zero4, 0, 0, 0);
#pragma unroll
            for (int j = 0; j < 4; ++j) {
                const int vk = vt * 16 + lhi * 4 + j;
                if (vk < 75) {
                    const int v = (vk >= 50) ? 2 : ((vk >= 25) ? 1 : 0);
                    const int k = vk - v * 25;
                    const float val = (k < 1) ? D[0][j]
                                    : (k < 4) ? D[1][j]
                                    : (k < 9) ? D[2][j]
                                    : (k < 16) ? D[3][j]
                                    : D[4][j];
                    const int ks = (k < 16) ? ((k >> 2) * 8 + (k & 3))
                                           : (((k - 16) >> 2) * 8 + 4 + ((k - 16) & 3));
                    hbs[(v * 32 + ct * 16 + llo) * HSTR + ks] = (f16)val;
                }
            }
        }
    }
    __syncthreads();

    // ---- hoist this wave's h fragments: tiles Rn = 2*vc + h (6 x v8h = 24 VGPR)
    v8h hfr[2][3];
    {
        const f16* hfb = &hb[llo * HSTR + lhi * 8];
#pragma unroll
        for (int s = 0; s < 2; ++s)
#pragma unroll
            for (int vc = 0; vc < 3; ++vc)
                hfr[s][vc] = *(const v8h*)(hfb + (s * 96 + (2 * vc + h) * 16) * HSTR);
    }

    v4f coacc[3][2];
#pragma unroll
    for (int vc = 0; vc < 3; ++vc)
#pragma unroll
        for (int t = 0; t < 2; ++t) coacc[vc][t] = zero4;

    union A2U { v2h p[4]; v8h v; };

    // packed-f16 cross for one gh (12 pkrtz + 12 pk ops)
    auto cross_gh = [&](const v4f (&ag)[2][3], A2U (&a2u)[3], int gh) {
        v2h g1[3][2], g2[3][2];
#pragma unroll
        for (int vc = 0; vc < 3; ++vc) {
            g1[vc][0] = pkrtz(ag[0][vc][0], ag[0][vc][1]);
            g1[vc][1] = pkrtz(ag[0][vc][2], ag[0][vc][3]);
            g2[vc][0] = pkrtz(ag[1][vc][0], ag[1][vc][1]);
            g2[vc][1] = pkrtz(ag[1][vc][2], ag[1][vc][3]);
        }
#pragma unroll
        for (int jp = 0; jp < 2; ++jp) {
            a2u[0].p[gh * 2 + jp] = g1[1][jp] * g2[2][jp] - g1[2][jp] * g2[1][jp];
            a2u[1].p[gh * 2 + jp] = g1[2][jp] * g2[0][jp] - g1[0][jp] * g2[2][jp];
            a2u[2].p[gh * 2 + jp] = g1[0][jp] * g2[1][jp] - g1[1][jp] * g2[0][jp];
        }
    };

    // one body: MFMA1 x12 -> cross -> MFMA2 x6
    auto body = [&](const v8h& a1lo, const v8h& a1hi, const v8h& b2lo, const v8h& b2hi) {
        A2U a2u[3];
#pragma unroll
        for (int gh = 0; gh < 2; ++gh) {
            const v8h a1 = gh ? a1hi : a1lo;
            v4f ag[2][3];
#pragma unroll
            for (int s = 0; s < 2; ++s)
#pragma unroll
                for (int vc = 0; vc < 3; ++vc)
                    ag[s][vc] = __builtin_amdgcn_mfma_f32_16x16x32_f16(
                        a1, hfr[s][vc], zero4, 0, 0, 0);
            cross_gh(ag, a2u, gh);
        }
#pragma unroll
        for (int vc = 0; vc < 3; ++vc) {
            coacc[vc][0] = __builtin_amdgcn_mfma_f32_16x16x32_f16(a2u[vc].v, b2lo, coacc[vc][0], 0, 0, 0);
            coacc[vc][1] = __builtin_amdgcn_mfma_f32_16x16x32_f16(a2u[vc].v, b2hi, coacc[vc][1], 0, 0, 0);
        }
    };

    // ---- main loop: wave (h,q) walks gb = q + 2*i; unroll-2 ping-pong sets
    if constexpr (USE_WS) {
        const v8h* base_a = (const v8h*)A1buf + lane;  // body i at offset (q+2i)*128
        const v8h* base_b = (const v8h*)B2buf + lane;
        const int iters = (NGB32 - q + 1) >> 1;        // q=0:32, q=1:31

        v8h A0a, A0b, B0a, B0b, A1a, A1b, B1a, B1b;
        {
            const v8h* pa = base_a + q * 128;
            const v8h* pb = base_b + q * 128;
            A0a = pa[0]; A0b = pa[64]; B0a = pb[0]; B0b = pb[64];
            const int gb1 = (iters > 1) ? (q + 2) : q;
            const v8h* pa1 = base_a + gb1 * 128;
            const v8h* pb1 = base_b + gb1 * 128;
            A1a = pa1[0]; A1b = pa1[64]; B1a = pb1[0]; B1b = pb1[64];
        }

        int i = 0;
        for (; i + 2 <= iters; i += 2) {
            body(A0a, A0b, B0a, B0b);
            {   // reload set0 for body i+2
                const int nb = i + 2;
                const int off = (nb < iters) ? (q + 2 * nb) * 128 : q * 128;
                const v8h* pa = base_a + off;
                const v8h* pb = base_b + off;
                A0a = pa[0]; A0b = pa[64]; B0a = pb[0]; B0b = pb[64];
            }
            body(A1a, A1b, B1a, B1b);
            {   // reload set1 for body i+3
                const int nb = i + 3;
                const int off = (nb < iters) ? (q + 2 * nb) * 128 : q * 128;
                const v8h* pa = base_a + off;
                const v8h* pb = base_b + off;
                A1a = pa[0]; A1b = pa[64]; B1a = pb[0]; B1b = pb[64];
            }
        }
        if (i < iters) body(A0a, A0b, B0a, B0b);
    } else {
        for (int gb = q; gb < NGB32; gb += 2) {
            v8h b20, b21, a10, a11;
#pragma unroll
            for (int j = 0; j < 8; ++j) {
                const int gg = gb * 32 + ((j < 4) ? (lhi * 4 + j) : (16 + lhi * 4 + (j - 4)));
                const float qg = qw[gg];
                b20[j] = (f16)(Y[llo * G_TOT + gg] * qg);
                const int k1 = 16 + llo;
                b21[j] = (f16)((k1 < 25) ? Y[k1 * G_TOT + gg] * qg : 0.0f);
                const int k = (j < 4) ? (lhi * 4 + j) : (16 + lhi * 4 + (j - 4));
                a10[j] = (f16)((k < 25) ? Y[k * G_TOT + gb * 32 + llo] : 0.0f);
                a11[j] = (f16)((k < 25) ? Y[k * G_TOT + gb * 32 + 16 + llo] : 0.0f);
            }
            body(a10, a11, b20, b21);
        }
    }

    // ---- CO: q=0 writes, q=1 accumulates (waves own disjoint rows across h)
    __syncthreads();
    if (q == 0) {
#pragma unroll
        for (int vc = 0; vc < 3; ++vc)
#pragma unroll
            for (int t = 0; t < 2; ++t)
#pragma unroll
                for (int j = 0; j < 4; ++j) {
                    const int row = (2 * vc + h) * 16 + lhi * 4 + j;
                    cob[row * CSTR + t * 16 + llo] = coacc[vc][t][j];
                }
    }
    __syncthreads();
    if (q == 1) {
#pragma unroll
        for (int vc = 0; vc < 3; ++vc)
#pragma unroll
            for (int t = 0; t < 2; ++t)
#pragma unroll
                for (int j = 0; j < 4; ++j) {
                    const int row = (2 * vc + h) * 16 + lhi * 4 + j;
                    cob[row * CSTR + t * 16 + llo] += coacc[vc][t][j];
                }
    }
    __syncthreads();

    // ---- epilogue: out[n, p*32+b, v, k] = sum_a co[v*32+a][k] * Wout[p,l_k,a,b]
    const float* Wop = Wouts + p * 5120;
    float* outp = out + (n * 96 + p * 32) * 75;
    for (int idx = tid; idx < 300; idx += 256) {
        const int vk = idx % 75, qq = idx / 75;
        const int v = vk / 25, k = vk - v * 25;
        const int l = (k >= 16) ? 4 : (k >= 9) ? 3 : (k >= 4) ? 2 : (k >= 1) ? 1 : 0;
        const float* w = Wop + l * 1024 + qq * 8;
        float acc[8];
#pragma unroll
        for (int b = 0; b < 8; ++b) acc[b] = 0.0f;
        for (int a = 0; a < 32; ++a) {
            const float cv = cob[(v * 32 + a) * CSTR + k];
#pragma unroll
            for (int b = 0; b < 8; ++b) acc[b] += cv * w[a * 32 + b];
        }
#pragma unroll
        for (int b = 0; b < 8; ++b) outp[(qq * 8 + b) * 75 + vk] = acc[b];
    }
}

extern "C" void kernel_launch(void* const* d_in, const int* in_sizes, int n_in,
                              void* d_out, int out_size, void* d_ws, size_t ws_size,
                              hipStream_t stream) {
    const float* x1 = (const float*)d_in[0];
    const float* x2 = (const float*)d_in[1];
    const float* W1s = (const float*)d_in[2];
    const float* W2s = (const float*)d_in[3];
    const float* Wouts = (const float*)d_in[4];
    const float* Y = (const float*)d_in[5];
    const float* qw = (const float*)d_in[6];
    float* out = (float*)d_out;

    f16* A1buf = (f16*)d_ws;
    f16* B2buf = (f16*)((char*)d_ws + 129024);

    if (ws_size >= 258048) {
        vg_prep<<<NGB32, 64, 0, stream>>>(Y, qw, A1buf, B2buf);
        vg_main<true><<<1536, 256, 0, stream>>>(x1, x2, W1s, W2s, Wouts, Y, qw,
                                                A1buf, B2buf, out);
    } else {
        vg_main<false><<<1536, 256, 0, stream>>>(x1, x2, W1s, W2s, Wouts, Y, qw,
                                                 nullptr, nullptr, out);
    }
}